// Round 1
// 1147.894 us; speedup vs baseline: 1.7796x; 1.7796x over previous
//
#include <hip/hip_runtime.h>
#include <hip/hip_bf16.h>

#define BATCH 2048
#define RES   7
#define NPOS  49
#define CDIM  512
#define HEADS 4
#define KD    32
#define DDIM  128
#define QO    192
#define EPS   1e-5f

// LDS row strides (floats). All fragment reads are ds_read_b128: strides are
// multiples of 4 (16B alignment) with gcd(S,32)=4 so the 16 row-lanes spread
// starts over all 32 banks (8 requests/bank = LDS-BW-bound, no extra serialization).
#define FS 132   // feat   [64][FS], K=128
#define QS 36    // qbuf/qcv/kbuf [64][QS], K=32
#define AS 68    // att    [64][AS], K=64 (cols 49..63 zeroed)
#define VS 68    // vT     [128][VS], K=64 (cols 49..63 zeroed)

typedef __attribute__((ext_vector_type(8))) short short8;   // 8 bf16
typedef __attribute__((ext_vector_type(4))) float floatx4;  // 4 fp32 acc

union S8u { short8 v; __hip_bfloat162 h[4]; };

__device__ inline short8 pack_bf16x8(float4 a, float4 b) {
    S8u u;
    u.h[0] = __float22bfloat162_rn(make_float2(a.x, a.y));
    u.h[1] = __float22bfloat162_rn(make_float2(a.z, a.w));
    u.h[2] = __float22bfloat162_rn(make_float2(b.x, b.y));
    u.h[3] = __float22bfloat162_rn(make_float2(b.z, b.w));
    return u.v;
}

// Error-compensated split: x = hi + lo (both bf16). A*B ~= Ah*Bh + Al*Bh + Ah*Bl
// keeps ~fp32 accuracy (lo*lo term ~2^-18 rel, dropped).
__device__ inline void split_pack8(float4 a, float4 b, short8& hi, short8& lo) {
    S8u H, L;
    float v0[8] = {a.x, a.y, a.z, a.w, b.x, b.y, b.z, b.w};
    #pragma unroll
    for (int p = 0; p < 4; ++p) {
        __hip_bfloat162 hp = __float22bfloat162_rn(make_float2(v0[2*p], v0[2*p+1]));
        float h0 = __bfloat162float(hp.x);
        float h1 = __bfloat162float(hp.y);
        H.h[p] = hp;
        L.h[p] = __float22bfloat162_rn(make_float2(v0[2*p] - h0, v0[2*p+1] - h1));
    }
    hi = H.v; lo = L.v;
}

#define MFMA(a, b, c) __builtin_amdgcn_mfma_f32_16x16x32_bf16((a), (b), (c), 0, 0, 0)

// One block per batch, 512 threads = 8 waves. Wave w: mt = w&3 (M-tile, rows
// 16mt..16mt+15 of the 49->64 padded position dim), nh = w>>2 (N-half).
// Fragment layouts mirror the harness-verified proj_mfma_kernel:
//   A[m=l15][k=quad*8+j], B[n=l15][k=quad*8+j], C/D[row=quad*4+r][col=l15].
__global__ __launch_bounds__(512, 2) void fused_cga_kernel(
    const float* __restrict__ x,
    const float* __restrict__ qkv_w,
    const float* __restrict__ qkv_g,  const float* __restrict__ qkv_bb,
    const float* __restrict__ qkv_m,  const float* __restrict__ qkv_v,
    const float* __restrict__ dw_w,
    const float* __restrict__ dw_g,   const float* __restrict__ dw_bb,
    const float* __restrict__ dw_m,   const float* __restrict__ dw_v,
    const float* __restrict__ proj_w,
    const float* __restrict__ proj_g, const float* __restrict__ proj_bb,
    const float* __restrict__ proj_m, const float* __restrict__ proj_v,
    const float* __restrict__ attn_bias,
    const int*   __restrict__ bias_idxs,
    float* __restrict__ out)
{
    __shared__ float feat[64 * FS];   // 33792 B, fp32 master; rows 49..63 zeroed once
    __shared__ float qbuf[64 * QS];   //  9216 B, q pre-conv (rows<49 used)
    __shared__ float qcv [64 * QS];   //  9216 B, q post-conv (QK^T A)
    __shared__ float kbuf[64 * QS];   //  9216 B, k (QK^T B)
    __shared__ float Wu  [6144];      // 24576 B union: att[64*AS] | qkvh/qkvl bf16 [192*32] x2
    __shared__ float U2  [128 * VS];  // 34816 B union: vT[128*VS] | Bl bf16 [512*32] | sp/tp
    __shared__ float sq[QO], tq[QO];
    __shared__ float wdw[KD * 25], sdw[KD], tdw[KD];
    // total 125824 B = 122.9 KiB -> 1 block/CU, 8 waves

    float* att = Wu;                               // [64][AS]
    unsigned short* qkvh = (unsigned short*)Wu;    // [192][32] bf16 hi
    unsigned short* qkvl = qkvh + QO * 32;         // [192][32] bf16 lo
    float* vT = U2;                                // [128][VS], vT[d][m] = v[m][d]
    unsigned short* Bl = (unsigned short*)U2;      // [512][32] bf16 proj_w K-tile

    const int b    = blockIdx.x;
    const int tid  = threadIdx.x;
    const int lane = tid & 63;
    const int wid  = tid >> 6;
    const int quad = lane >> 4;
    const int l15  = lane & 15;
    const int mt   = wid & 3;
    const int nh   = wid >> 2;

    const float* xb = x + (size_t)b * NPOS * CDIM;

    // Persistent proj accumulators: wave covers rows [16mt,16mt+16) x cols [256nh, 256nh+256).
    floatx4 po[16];
    #pragma unroll
    for (int t = 0; t < 16; ++t) po[t] = (floatx4){0.f, 0.f, 0.f, 0.f};

    // Zero feat pad rows once (read as A-fragments for the discarded M-rows).
    for (int i = tid; i < 15 * FS; i += 512) feat[49 * FS + i] = 0.f;

    for (int head = 0; head < HEADS; ++head) {
        // ---- P1: cascade feat update + per-head BN params / dw weights into LDS
        for (int i = tid; i < NPOS * (DDIM / 4); i += 512) {
            int n = i >> 5, c4 = i & 31;
            float4 xv = *(const float4*)(xb + n * CDIM + head * DDIM + c4 * 4);
            float* fp = feat + n * FS + c4 * 4;
            if (head == 0) { *(float4*)fp = xv; }
            else {
                float4 f = *(float4*)fp;
                f.x += xv.x; f.y += xv.y; f.z += xv.z; f.w += xv.w;
                *(float4*)fp = f;
            }
        }
        if (tid < QO) {
            float s = qkv_g[head * QO + tid] * rsqrtf(qkv_v[head * QO + tid] + EPS);
            sq[tid] = s;
            tq[tid] = qkv_bb[head * QO + tid] - qkv_m[head * QO + tid] * s;
        } else if (tid < QO + KD) {
            int ch = tid - QO;
            float s = dw_g[head * KD + ch] * rsqrtf(dw_v[head * KD + ch] + EPS);
            sdw[ch] = s;
            tdw[ch] = dw_bb[head * KD + ch] - dw_m[head * KD + ch] * s;
        }
        for (int i = tid; i < KD * 25; i += 512) wdw[i] = dw_w[head * KD * 25 + i];
        __syncthreads();

        // ---- P2: QKV = feat @ Wqkv^T  (M=64, N=192, K=128), split-bf16 MFMA.
        // Wqkv K-tile staged once per block (hi/lo) -> kills 4x redundant L2 reads+converts.
        {
            floatx4 qa[6];
            #pragma unroll
            for (int t = 0; t < 6; ++t) qa[t] = (floatx4){0.f, 0.f, 0.f, 0.f};
            for (int ks = 0; ks < 4; ++ks) {
                for (int i = tid; i < QO * 4; i += 512) {         // 768 items, 8 floats each
                    int rowi = i >> 2, j8 = i & 3;
                    const float* wp = qkv_w + (size_t)(head * QO + rowi) * DDIM + ks * 32 + j8 * 8;
                    short8 h8, l8;
                    split_pack8(*(const float4*)wp, *(const float4*)(wp + 4), h8, l8);
                    *(short8*)(qkvh + rowi * 32 + j8 * 8) = h8;
                    *(short8*)(qkvl + rowi * 32 + j8 * 8) = l8;
                }
                __syncthreads();
                const float* ap = feat + (mt * 16 + l15) * FS + ks * 32 + quad * 8;
                short8 ah, al;
                split_pack8(*(const float4*)ap, *(const float4*)(ap + 4), ah, al);
                #pragma unroll
                for (int t = 0; t < 6; ++t) {
                    int rw = (nh * 96 + t * 16 + l15) * 32 + quad * 8;
                    short8 bh = *(const short8*)(qkvh + rw);
                    short8 bl = *(const short8*)(qkvl + rw);
                    qa[t] = MFMA(ah, bh, qa[t]);
                    qa[t] = MFMA(al, bh, qa[t]);
                    qa[t] = MFMA(ah, bl, qa[t]);
                }
                __syncthreads();
            }
            // epilogue: BN then route q / k / v(transposed). kind is uniform per t.
            #pragma unroll
            for (int t = 0; t < 6; ++t) {
                int o = nh * 96 + t * 16 + l15;
                float s = sq[o], tt = tq[o];
                #pragma unroll
                for (int r = 0; r < 4; ++r) {
                    int row = mt * 16 + quad * 4 + r;
                    if (row < NPOS) {
                        float y = qa[t][r] * s + tt;
                        if (o < KD)          qbuf[row * QS + o] = y;
                        else if (o < 2 * KD) kbuf[row * QS + (o - KD)] = y;
                        else                 vT[(o - 2 * KD) * VS + row] = y;
                    }
                }
            }
        }
        __syncthreads();

        // ---- P3: depthwise 5x5 conv + BN -> qcv (fp32, tiny)
        for (int i = tid; i < NPOS * KD; i += 512) {
            int n = i >> 5, ch = i & 31;
            int rr = n / RES, cc = n - rr * RES;
            float acc = 0.f;
            #pragma unroll
            for (int dy = 0; dy < 5; ++dy) {
                int ry = rr + dy - 2;
                if (ry < 0 || ry >= RES) continue;
                #pragma unroll
                for (int dx = 0; dx < 5; ++dx) {
                    int cx = cc + dx - 2;
                    if (cx < 0 || cx >= RES) continue;
                    acc += qbuf[(ry * RES + cx) * QS + ch] * wdw[ch * 25 + dy * 5 + dx];
                }
            }
            qcv[n * QS + ch] = acc * sdw[ch] + tdw[ch];
        }
        __syncthreads();

        // ---- P4: att = qcv @ kbuf^T * scale + bias  (M=64, N=64, K=32), split-bf16.
        // Lanes with col in [49,64) write 0 -> zero-pads att's K dim for PV.
        {
            floatx4 sa[2];
            sa[0] = (floatx4){0.f, 0.f, 0.f, 0.f};
            sa[1] = (floatx4){0.f, 0.f, 0.f, 0.f};
            const float* ap = qcv + (mt * 16 + l15) * QS + quad * 8;
            short8 ah, al;
            split_pack8(*(const float4*)ap, *(const float4*)(ap + 4), ah, al);
            #pragma unroll
            for (int t = 0; t < 2; ++t) {
                const float* kp = kbuf + ((nh * 2 + t) * 16 + l15) * QS + quad * 8;
                short8 bh, bl;
                split_pack8(*(const float4*)kp, *(const float4*)(kp + 4), bh, bl);
                sa[t] = MFMA(ah, bh, sa[t]);
                sa[t] = MFMA(al, bh, sa[t]);
                sa[t] = MFMA(ah, bl, sa[t]);
            }
            const float scale = 0.17677669529663687f;
            #pragma unroll
            for (int t = 0; t < 2; ++t) {
                int nn = (nh * 2 + t) * 16 + l15;
                #pragma unroll
                for (int r = 0; r < 4; ++r) {
                    int row = mt * 16 + quad * 4 + r;
                    if (row < NPOS) {
                        if (nn < NPOS)
                            att[row * AS + nn] = sa[t][r] * scale
                                + attn_bias[head * NPOS + bias_idxs[row * NPOS + nn]];
                        else if (nn < 64)
                            att[row * AS + nn] = 0.f;
                    }
                }
            }
        }
        __syncthreads();

        // ---- P5: softmax (8 lanes per row, shfl-xor reduce) + re-zero vT pad cols
        {
            int row = tid >> 3, g = tid & 7;
            if (row < NPOS) {
                float mx = -1e30f;
                for (int n = g; n < NPOS; n += 8) mx = fmaxf(mx, att[row * AS + n]);
                #pragma unroll
                for (int d = 1; d < 8; d <<= 1) mx = fmaxf(mx, __shfl_xor(mx, d));
                float sm = 0.f;
                for (int n = g; n < NPOS; n += 8) {
                    float e = __expf(att[row * AS + n] - mx);
                    att[row * AS + n] = e;
                    sm += e;
                }
                #pragma unroll
                for (int d = 1; d < 8; d <<= 1) sm += __shfl_xor(sm, d);
                float inv = 1.f / sm;
                for (int n = g; n < NPOS; n += 8) att[row * AS + n] *= inv;
            }
            // vT cols 49..67 must be zero before PV (region was P7's Bl last head)
            for (int i = tid; i < 128 * 19; i += 512) {
                int d = i / 19, m2 = i - d * 19 + 49;
                vT[d * VS + m2] = 0.f;
            }
        }
        __syncthreads();

        // ---- P6: feat = att @ v  (M=64, N=128, K=64), split-bf16. B[n=d][k=m] = vT.
        {
            floatx4 pa[4];
            #pragma unroll
            for (int t = 0; t < 4; ++t) pa[t] = (floatx4){0.f, 0.f, 0.f, 0.f};
            #pragma unroll
            for (int ks = 0; ks < 2; ++ks) {
                const float* ap = att + (mt * 16 + l15) * AS + ks * 32 + quad * 8;
                short8 ah, al;
                split_pack8(*(const float4*)ap, *(const float4*)(ap + 4), ah, al);
                #pragma unroll
                for (int t = 0; t < 4; ++t) {
                    const float* vp = vT + ((nh * 4 + t) * 16 + l15) * VS + ks * 32 + quad * 8;
                    short8 bh, bl;
                    split_pack8(*(const float4*)vp, *(const float4*)(vp + 4), bh, bl);
                    pa[t] = MFMA(ah, bh, pa[t]);
                    pa[t] = MFMA(al, bh, pa[t]);
                    pa[t] = MFMA(ah, bl, pa[t]);
                }
            }
            #pragma unroll
            for (int t = 0; t < 4; ++t) {
                int d = (nh * 4 + t) * 16 + l15;
                #pragma unroll
                for (int r = 0; r < 4; ++r) {
                    int row = mt * 16 + quad * 4 + r;
                    if (row < NPOS) feat[row * FS + d] = pa[t][r];
                }
            }
        }
        __syncthreads();

        // ---- P7: proj accumulate: po += bf16(relu(feat)) @ bf16(Wp[:,head*128:])^T
        // (plain bf16 both sides == current kernel's proj precision). Wp K-tile staged
        // in LDS per (head,ks): proj_w read exactly once per block.
        for (int ks = 0; ks < 4; ++ks) {
            for (int it = tid; it < CDIM * 8; it += 512) {        // 4096 float4 items
                int rowi = it >> 3, j4 = it & 7;
                float4 w = *(const float4*)(proj_w + (size_t)rowi * CDIM + head * DDIM + ks * 32 + j4 * 4);
                __hip_bfloat162 p0 = __float22bfloat162_rn(make_float2(w.x, w.y));
                __hip_bfloat162 p1 = __float22bfloat162_rn(make_float2(w.z, w.w));
                unsigned short* dp = Bl + rowi * 32 + j4 * 4;
                *(__hip_bfloat162*)dp       = p0;
                *(__hip_bfloat162*)(dp + 2) = p1;
            }
            __syncthreads();
            {
                const float* ap = feat + (mt * 16 + l15) * FS + ks * 32 + quad * 8;
                float4 a0 = *(const float4*)ap;
                float4 a1 = *(const float4*)(ap + 4);
                a0.x = fmaxf(a0.x, 0.f); a0.y = fmaxf(a0.y, 0.f);
                a0.z = fmaxf(a0.z, 0.f); a0.w = fmaxf(a0.w, 0.f);
                a1.x = fmaxf(a1.x, 0.f); a1.y = fmaxf(a1.y, 0.f);
                a1.z = fmaxf(a1.z, 0.f); a1.w = fmaxf(a1.w, 0.f);
                short8 af = pack_bf16x8(a0, a1);
                #pragma unroll
                for (int t = 0; t < 16; ++t) {
                    short8 bf = *(const short8*)(Bl + ((nh * 256 + t * 16 + l15) << 5) + quad * 8);
                    po[t] = __builtin_amdgcn_mfma_f32_16x16x32_bf16(af, bf, po[t], 0, 0, 0);
                }
            }
            __syncthreads();
        }
    }

    // ---- final epilogue: proj BN + store (Bl region is dead -> stage s/t there)
    float* sp = U2;
    float* tp = U2 + 512;
    {
        int o = tid;   // exactly 512 threads
        float s = proj_g[o] * rsqrtf(proj_v[o] + EPS);
        sp[o] = s;
        tp[o] = proj_bb[o] - proj_m[o] * s;
    }
    __syncthreads();
    #pragma unroll
    for (int t = 0; t < 16; ++t) {
        int o = nh * 256 + t * 16 + l15;
        float s = sp[o], tt = tp[o];
        #pragma unroll
        for (int r = 0; r < 4; ++r) {
            int row = mt * 16 + quad * 4 + r;
            if (row < NPOS)
                out[((size_t)b * NPOS + row) * CDIM + o] = po[t][r] * s + tt;
        }
    }
}

// ---------------------------------------------------------------------------
extern "C" void kernel_launch(void* const* d_in, const int* in_sizes, int n_in,
                              void* d_out, int out_size, void* d_ws, size_t ws_size,
                              hipStream_t stream) {
    const float* x      = (const float*)d_in[0];
    const float* qkv_w  = (const float*)d_in[1];
    const float* qkv_g  = (const float*)d_in[2];
    const float* qkv_b  = (const float*)d_in[3];
    const float* qkv_m  = (const float*)d_in[4];
    const float* qkv_v  = (const float*)d_in[5];
    const float* dw_w   = (const float*)d_in[6];
    const float* dw_g   = (const float*)d_in[7];
    const float* dw_b   = (const float*)d_in[8];
    const float* dw_m   = (const float*)d_in[9];
    const float* dw_v   = (const float*)d_in[10];
    const float* proj_w = (const float*)d_in[11];
    const float* proj_g = (const float*)d_in[12];
    const float* proj_b = (const float*)d_in[13];
    const float* proj_m = (const float*)d_in[14];
    const float* proj_v = (const float*)d_in[15];
    const float* attn_bias = (const float*)d_in[16];
    const int*   bias_idxs = (const int*)d_in[17];
    float* out = (float*)d_out;
    (void)d_ws; (void)ws_size;   // R2 lesson: d_ws too small — unused.

    hipLaunchKernelGGL(fused_cga_kernel, dim3(BATCH), dim3(512), 0, stream,
        x, qkv_w, qkv_g, qkv_b, qkv_m, qkv_v,
        dw_w, dw_g, dw_b, dw_m, dw_v,
        proj_w, proj_g, proj_b, proj_m, proj_v,
        attn_bias, bias_idxs, out);
}